// Round 1
// 932.214 us; speedup vs baseline: 1.1452x; 1.1452x over previous
//
#include <hip/hip_runtime.h>
#include <stdint.h>

// ---- problem constants -----------------------------------------------------
// B=32768, D=2048, L=64, SOM 8x8=64 codes. All inputs fp32.
// d_out layout (fp32 elements), in reference return order:
//   x_e[B,D], x_q[B,D], z_e[B,64], z_q[B,64], z_q_neighbors[B,5,64], k[B], z_dist[B,64]
constexpr size_t OFF_XQ = (size_t)32768 * 2048;           //  67108864
constexpr size_t OFF_ZE = OFF_XQ * 2;                     // 134217728
constexpr size_t OFF_ZQ = OFF_ZE + (size_t)32768 * 64;    // 136314880
constexpr size_t OFF_NB = OFF_ZQ + (size_t)32768 * 64;    // 138412032
constexpr size_t OFF_K  = OFF_NB + (size_t)32768 * 5 * 64;// 148897792
constexpr size_t OFF_ZD = OFF_K + 32768;                  // 148930560

typedef __attribute__((ext_vector_type(8))) short short8;
typedef __attribute__((ext_vector_type(4))) float f32x4;
typedef __attribute__((ext_vector_type(4))) unsigned short us4;

__device__ __forceinline__ unsigned short f2bf(float f) {
  unsigned int u = __float_as_uint(f);
  u += 0x7fffu + ((u >> 16) & 1u);        // round-to-nearest-even
  return (unsigned short)(u >> 16);
}

// ---- kernel 0: transpose+convert W_dec_{e,q} [64,2048] -> WT bf16 [2048,64] -
__global__ __launch_bounds__(256) void somvae_wprep(
    const float* __restrict__ We, const float* __restrict__ Wq,
    unsigned short* __restrict__ wt)
{
  const int sel = blockIdx.y;
  const float* W = sel ? Wq : We;
  unsigned short* WT = wt + (size_t)sel * (64 * 2048);
  const int d0 = blockIdx.x * 64;
  __shared__ unsigned short tl[64][68];   // [dd][l] bf16, stride 68 for 8B-aligned reads
  const int t = threadIdx.x;
  for (int i = 4 * t; i < 4096; i += 1024) {
    int l = i >> 6, dd = i & 63;
    float4 v = *(const float4*)(W + (size_t)l * 2048 + d0 + dd);
    tl[dd + 0][l] = f2bf(v.x);
    tl[dd + 1][l] = f2bf(v.y);
    tl[dd + 2][l] = f2bf(v.z);
    tl[dd + 3][l] = f2bf(v.w);
  }
  __syncthreads();
  {
    int dd = t >> 2, c4 = (t & 3) * 16;
    #pragma unroll
    for (int q = 0; q < 4; ++q) {
      us4 v;
      v.x = tl[dd][c4 + 4 * q + 0];
      v.y = tl[dd][c4 + 4 * q + 1];
      v.z = tl[dd][c4 + 4 * q + 2];
      v.w = tl[dd][c4 + 4 * q + 3];
      *(us4*)(WT + (size_t)(d0 + dd) * 64 + c4 + 4 * q) = v;
    }
  }
}

// ---- fused kernel: encoder GEMM (fp32) + SOM argmin + both decoders --------
// grid 512 blocks x 256 thr; each block owns 64 rows end-to-end.
// GEMM: 2 k-groups x (8 row-threads x 16 col-threads), 8x4 microtile,
//       row-major x staging (no transpose scatter), rows strided by 8.
// Decode: MFMA with A = W^T tile (d rows), B = z rows -> float4 stores.
__global__ __launch_bounds__(256, 2) void somvae_fused(
    const float* __restrict__ x, const float* __restrict__ W_enc,
    const float* __restrict__ b_enc, const float* __restrict__ emb,
    const float* __restrict__ Wq, const float* __restrict__ bq,
    const float* __restrict__ We, const float* __restrict__ be,
    const unsigned short* __restrict__ wt, int use_wt,
    float* __restrict__ out)
{
  __shared__ float xs[64][68];     // x tile, row-major [row][k]
  __shared__ float ws[64][68];     // W_enc tile [k][j]; reused as zs[row][j] after GEMM
  __shared__ float Erow[64][68];   // [code][j]
  __shared__ double eeD[64];       // |e_c|^2 in fp64
  __shared__ int kidxs[64];        // argmin code per row (for z_q decode)

  const int t = threadIdx.x;
  const int row0 = blockIdx.x * 64;

  // stage embeddings (64x64) once
  for (int i = 4 * t; i < 4096; i += 1024) {
    float4 v = *(const float4*)(emb + i);
    *(float4*)&Erow[i >> 6][i & 63] = v;
  }
  __syncthreads();
  if (t < 64) {
    double s = 0.0;
    #pragma unroll
    for (int j = 0; j < 64; ++j) { double v = (double)Erow[t][j]; s += v * v; }
    eeD[t] = s;
  }

  // ---- phase 1: z_e = x @ W_enc (fp32), K split across 2 thread-groups ----
  const int kg = t >> 7;          // k-group 0/1 (k in [kg*32, kg*32+32) of each chunk)
  const int ty = (t >> 4) & 7;    // row-thread: rows {ty + 8i}
  const int tx = t & 15;          // col-thread: cols 4*tx..4*tx+3
  const int srow = t >> 2;        // staging row 0..63
  const int scol = (t & 3) * 16;  // staging col chunk

  float acc[8][4] = {};
  for (int kb = 0; kb < 2048; kb += 64) {
    __syncthreads();
    #pragma unroll
    for (int q = 0; q < 4; ++q) {
      *(float4*)&xs[srow][scol + 4 * q] =
          *(const float4*)(x + (size_t)(row0 + srow) * 2048 + kb + scol + 4 * q);
      *(float4*)&ws[srow][scol + 4 * q] =
          *(const float4*)(W_enc + (size_t)(kb + srow) * 64 + scol + 4 * q);
    }
    __syncthreads();
    const int k0 = kg * 32;
    #pragma unroll
    for (int kq = 0; kq < 8; ++kq) {
      const int kbq = k0 + 4 * kq;
      f32x4 wv[4];
      #pragma unroll
      for (int kk = 0; kk < 4; ++kk)
        wv[kk] = *(const f32x4*)&ws[kbq + kk][4 * tx];
      #pragma unroll
      for (int i = 0; i < 8; ++i) {
        f32x4 a = *(const f32x4*)&xs[ty + 8 * i][kbq];
        #pragma unroll
        for (int kk = 0; kk < 4; ++kk)
          #pragma unroll
          for (int j = 0; j < 4; ++j)
            acc[i][j] = fmaf(a[kk], wv[kk][j], acc[i][j]);
      }
    }
  }

  // merge the two K-halves into zs (= ws reuse), add bias, write z_e
  __syncthreads();                 // all GEMM reads of ws done
  float (*zs)[68] = ws;
  if (kg == 1) {
    #pragma unroll
    for (int i = 0; i < 8; ++i) {
      f32x4 av = {acc[i][0], acc[i][1], acc[i][2], acc[i][3]};
      *(f32x4*)&zs[ty + 8 * i][4 * tx] = av;
    }
  }
  __syncthreads();
  if (kg == 0) {
    f32x4 be4 = *(const f32x4*)(b_enc + 4 * tx);
    #pragma unroll
    for (int i = 0; i < 8; ++i) {
      const int r = ty + 8 * i;
      f32x4 v = *(const f32x4*)&zs[r][4 * tx];
      #pragma unroll
      for (int j = 0; j < 4; ++j) v[j] = v[j] + acc[i][j] + be4[j];
      *(f32x4*)&zs[r][4 * tx] = v;
      *(f32x4*)(out + OFF_ZE + (size_t)(row0 + r) * 64 + 4 * tx) = v;
    }
  }
  __syncthreads();

  // ---- phase 2: distances / argmin / gather (per-wave, 64 lanes = 64 codes) -
  const int lane = t & 63;
  {
    const int rbase = (t >> 6) * 16;
    for (int rr = 0; rr < 16; ++rr) {
      const int r = rbase + rr;
      float dotf = 0.f, sf = 0.f;
      #pragma unroll
      for (int j4 = 0; j4 < 64; j4 += 4) {
        f32x4 z4 = *(const f32x4*)&zs[r][j4];      // broadcast
        f32x4 e4 = *(const f32x4*)&Erow[lane][j4];
        dotf = fmaf(z4[0], e4[0], dotf); dotf = fmaf(z4[1], e4[1], dotf);
        dotf = fmaf(z4[2], e4[2], dotf); dotf = fmaf(z4[3], e4[3], dotf);
        sf = fmaf(z4[0], z4[0], sf); sf = fmaf(z4[1], z4[1], sf);
        sf = fmaf(z4[2], z4[2], sf); sf = fmaf(z4[3], z4[3], sf);
      }
      // sf is per-row constant across lanes => cannot affect argmin ordering;
      // combine in fp64 so ordering noise is ~1e-16 * |d|.
      double d = (double)sf - 2.0 * (double)dotf + eeD[lane];
      double bd = d; int bi = lane;
      #pragma unroll
      for (int off = 32; off; off >>= 1) {
        double od = __shfl_xor(bd, off, 64);
        int    oi = __shfl_xor(bi, off, 64);
        if (od < bd || (od == bd && oi < bi)) { bd = od; bi = oi; }
      }
      const int k  = bi;           // first index of min (tie-low), all lanes agree
      const int k1 = k >> 3, k2 = k & 7;
      const size_t row = (size_t)(row0 + r);
      const int kup = (k1 < 7) ? k + 8 : k;
      const int kdn = (k1 > 0) ? k - 8 : k;
      const int klf = (k2 > 0) ? k - 1 : k;
      float zq = Erow[k][lane];
      out[OFF_ZQ + row * 64 + lane] = zq;
      const size_t nb = OFF_NB + row * 320;
      out[nb +   0 + lane] = zq;
      out[nb +  64 + lane] = (k1 < 7) ? Erow[kup][lane] : 0.f;
      out[nb + 128 + lane] = (k1 > 0) ? Erow[kdn][lane] : 0.f;
      out[nb + 192 + lane] = 0.f;                         // faithful `==` bug: right = 0
      out[nb + 256 + lane] = (k2 > 0) ? Erow[klf][lane] : 0.f;
      out[OFF_ZD + row * 64 + lane] = (float)d;
      if (lane == 0) { out[OFF_K + row] = (float)k; kidxs[r] = k; }
    }
  }
  __syncthreads();

  // ---- phase 3: decoders. A = W^T tile (d rows), B = z rows -> D[d][brow].
  // Each lane holds 4 consecutive d for one batch row -> one float4 store.
  {
    const int w = t >> 6;
    const int m = lane & 15, quad = lane >> 4;
    for (int sel = 0; sel < 2; ++sel) {            // 0: x_e (z_e), 1: x_q (z_q)
      const float* bias = sel ? bq : be;
      const float* Wf   = sel ? Wq : We;           // fallback path, fp32 [64][2048]
      const unsigned short* WTs = wt + (size_t)sel * (64 * 2048);
      float* xo = out + (sel ? OFF_XQ : (size_t)0);

      // B fragments from LDS: 4 row-groups x 2 k-halves, bf16-packed
      short8 bz[4][2];
      #pragma unroll
      for (int rg = 0; rg < 4; ++rg) {
        const int br = rg * 16 + m;
        const float* zp = sel ? &Erow[kidxs[br]][0] : &zs[br][0];
        #pragma unroll
        for (int h = 0; h < 2; ++h) {
          f32x4 u0 = *(const f32x4*)(zp + 32 * h + quad * 8);
          f32x4 u1 = *(const f32x4*)(zp + 32 * h + quad * 8 + 4);
          short8 b;
          b[0] = (short)f2bf(u0[0]); b[1] = (short)f2bf(u0[1]);
          b[2] = (short)f2bf(u0[2]); b[3] = (short)f2bf(u0[3]);
          b[4] = (short)f2bf(u1[0]); b[5] = (short)f2bf(u1[1]);
          b[6] = (short)f2bf(u1[2]); b[7] = (short)f2bf(u1[3]);
          bz[rg][h] = b;
        }
      }

      for (int dt = w; dt < 128; dt += 4) {        // 16-d tiles, waves interleaved
        const int d0 = dt * 16;
        short8 a0, a1;                             // A[d=d0+m][k], k halves
        if (use_wt) {
          const unsigned short* wp = WTs + (size_t)(d0 + m) * 64 + quad * 8;
          a0 = *(const short8*)(wp);
          a1 = *(const short8*)(wp + 32);
        } else {
          #pragma unroll
          for (int j = 0; j < 8; ++j) {
            a0[j] = (short)f2bf(Wf[(size_t)(quad * 8 + j) * 2048 + d0 + m]);
            a1[j] = (short)f2bf(Wf[(size_t)(32 + quad * 8 + j) * 2048 + d0 + m]);
          }
        }
        f32x4 bv = *(const f32x4*)(bias + d0 + quad * 4);
        #pragma unroll
        for (int rg = 0; rg < 4; ++rg) {
          f32x4 acc2 = {0.f, 0.f, 0.f, 0.f};
          acc2 = __builtin_amdgcn_mfma_f32_16x16x32_bf16(a0, bz[rg][0], acc2, 0, 0, 0);
          acc2 = __builtin_amdgcn_mfma_f32_16x16x32_bf16(a1, bz[rg][1], acc2, 0, 0, 0);
          // D: col = lane&15 = batch row (rg*16+m), row = quad*4+reg = d offset
          #pragma unroll
          for (int j = 0; j < 4; ++j) acc2[j] += bv[j];
          *(f32x4*)(xo + (size_t)(row0 + rg * 16 + m) * 2048 + d0 + quad * 4) = acc2;
        }
      }
    }
  }
}

extern "C" void kernel_launch(void* const* d_in, const int* in_sizes, int n_in,
                              void* d_out, int out_size, void* d_ws, size_t ws_size,
                              hipStream_t stream) {
  (void)in_sizes; (void)n_in; (void)out_size;
  const float* x       = (const float*)d_in[0];
  const float* W_enc   = (const float*)d_in[1];
  const float* b_enc   = (const float*)d_in[2];
  const float* W_dec_q = (const float*)d_in[3];
  const float* b_dec_q = (const float*)d_in[4];
  const float* W_dec_e = (const float*)d_in[5];
  const float* b_dec_e = (const float*)d_in[6];
  const float* emb     = (const float*)d_in[7];
  float* out = (float*)d_out;
  unsigned short* wt = (unsigned short*)d_ws;
  const int use_wt = (ws_size >= (size_t)2 * 64 * 2048 * sizeof(unsigned short)) ? 1 : 0;

  if (use_wt)
    somvae_wprep<<<dim3(32, 2), 256, 0, stream>>>(W_dec_e, W_dec_q, wt);
  somvae_fused<<<dim3(512), 256, 0, stream>>>(x, W_enc, b_enc, emb,
                                              W_dec_q, b_dec_q, W_dec_e, b_dec_e,
                                              wt, use_wt, out);
}